// Round 3
// baseline (497.851 us; speedup 1.0000x reference)
//
#include <hip/hip_runtime.h>
#include <math.h>

#define NN 100000
#define DIN 256
#define DH 128
#define GEMM_NB 1563       // ceil(NN/64)
#define BSHIFT 9
#define BNODES 512                     // nodes per bucket
#define NB_BUCKET 196                  // ceil(NN/512)
#define BCAP 12288                     // bucket capacity (mean 8163, sigma ~90)
#define PA_EDGES 8192                  // edges per pass-A block
#define PREP_NB 64                     // prepW blocks at 512 threads

using short8  = __attribute__((ext_vector_type(8))) short;
using float4v = __attribute__((ext_vector_type(4))) float;

static __device__ __forceinline__ unsigned short f2bf(float f) {
    unsigned u = __float_as_uint(f);
    unsigned r = u + 0x7fffu + ((u >> 16) & 1u);   // round-to-nearest-even
    return (unsigned short)(r >> 16);
}
static __device__ __forceinline__ float bf_lo(unsigned u) { return __uint_as_float(u << 16); }
static __device__ __forceinline__ float bf_hi(unsigned u) { return __uint_as_float(u & 0xffff0000u); }

// ---------------- fused: W1 pre-swizzle (blocks 0..63)  ||  pass A (blocks 64..) ----------------
__global__ __launch_bounds__(512) void k_prep_partA(const float* __restrict__ W1,
                                                    unsigned short* __restrict__ W1p,
                                                    const int* __restrict__ src,
                                                    const int* __restrict__ dst, int E,
                                                    int* __restrict__ bucketFill,
                                                    int2* __restrict__ bucketArr) {
    __shared__ int aCnt[NB_BUCKET];
    __shared__ int aBase[NB_BUCKET];
    const int tid = threadIdx.x;

    if (blockIdx.x < PREP_NB) {
        // ---- prepW: identical t-space as the validated 128x256 version ----
        int t = blockIdx.x * 512 + tid;             // 0..32767
        int lane = t & 63;
        int ks   = (t >> 6) & 7;
        int nt   = (t >> 9) & 1;
        int wv   = (t >> 10) & 3;
        int n = wv * 32 + nt * 16 + (lane & 15);
        int kbase = ks * 32 + (lane >> 4) * 8;
        short8 v;
#pragma unroll
        for (int j = 0; j < 8; ++j) v[j] = (short)f2bf(W1[(kbase + j) * DH + n]);
        *(short8*)&W1p[(long long)t * 8] = v;
        return;
    }

    // ---- pass A: partition 8192 edges into dst-range buckets ----
    const int ba = blockIdx.x - PREP_NB;
    for (int i = tid; i < NB_BUCKET; i += 512) aCnt[i] = 0;
    __syncthreads();
    const int e0   = ba * PA_EDGES;
    const int eend = min(e0 + PA_EDGES, E);
    for (int e = e0 + tid; e < eend; e += 512)
        atomicAdd(&aCnt[dst[e] >> BSHIFT], 1);
    __syncthreads();
    for (int i = tid; i < NB_BUCKET; i += 512) {
        int c = aCnt[i];
        aBase[i] = c ? atomicAdd(&bucketFill[i], c) : 0;
        aCnt[i] = 0;   // reuse as cursor
    }
    __syncthreads();
    for (int e = e0 + tid; e < eend; e += 512) {
        int d = dst[e];
        int b = d >> BSHIFT;
        int s = __builtin_nontemporal_load(&src[e]);   // read-once stream
        int r = atomicAdd(&aCnt[b], 1);
        bucketArr[(long long)b * BCAP + aBase[b] + r] = make_int2(s, d);
    }
}

// ---------------- fused: pass B (blocks 0..195)  ||  GEMM hs=x@W1 (blocks 196..) ----------------
// GEMM writes hs in SLICED layout: hs_s[slice=w8][node][16 bf16] (slice stride NN*16).
__global__ __launch_bounds__(512) void k_gemm_partB(const float* __restrict__ x,
                                                    const unsigned short* __restrict__ W1p,
                                                    unsigned short* __restrict__ hs,
                                                    const int* __restrict__ bucketFill,
                                                    const int2* __restrict__ bucketArr,
                                                    int* __restrict__ cnt,
                                                    int* __restrict__ excl,
                                                    float* __restrict__ dinv,
                                                    int* __restrict__ eidx) {
    __shared__ unsigned short aL[64 * 32 * 8];   // 32 KB (gemm path)
    __shared__ int h[BNODES];                    // partB path
    __shared__ int hex[BNODES];
    __shared__ int st[256];
    const int tid = threadIdx.x;

    if (blockIdx.x < NB_BUCKET) {
        // ---- pass B: per-bucket local CSR build ----
        const int b     = blockIdx.x;
        const int nbase = b << BSHIFT;
        const int len   = bucketFill[b];
        const long long abase = (long long)b * BCAP;

        // gbase = sum(bucketFill[0..b-1]) via block reduction
        if (tid < 256) st[tid] = (tid < b) ? bucketFill[tid] : 0;
        __syncthreads();
        for (int off = 128; off > 0; off >>= 1) {
            if (tid < off) st[tid] += st[tid + off];
            __syncthreads();
        }
        const int gbase = st[0];
        __syncthreads();

        for (int i = tid; i < BNODES; i += 512) h[i] = 0;
        __syncthreads();
        for (int k = tid; k < len; k += 512)
            atomicAdd(&h[bucketArr[abase + k].y - nbase], 1);
        __syncthreads();

        // scan 512 counters: pairwise + Hillis-Steele over 256 pair sums
        int a0 = 0, a1 = 0;
        if (tid < 256) {
            a0 = h[2 * tid]; a1 = h[2 * tid + 1];
            st[tid] = a0 + a1;
        }
        __syncthreads();
        for (int off = 1; off < 256; off <<= 1) {
            int val = (tid < 256 && tid >= off) ? st[tid - off] : 0;
            __syncthreads();
            if (tid < 256) st[tid] += val;
            __syncthreads();
        }
        if (tid < 256) {
            int prev = (tid > 0) ? st[tid - 1] : 0;
            hex[2 * tid]     = prev;
            hex[2 * tid + 1] = prev + a0;
        }
        __syncthreads();

        for (int i = tid; i < BNODES; i += 512) {
            int n = nbase + i;
            if (n < NN) {
                int c = h[i];
                cnt[n]  = c;
                excl[n] = gbase + hex[i];
                dinv[n] = rsqrtf(1.0f + (float)c);
            }
        }
        for (int i = tid; i < BNODES; i += 512) h[i] = 0;   // cursors
        __syncthreads();

        for (int k = tid; k < len; k += 512) {
            int2 p = bucketArr[abase + k];
            int li = p.y - nbase;
            int r = atomicAdd(&h[li], 1);
            eidx[gbase + hex[li] + r] = p.x;
        }
        return;
    }

    // ---- GEMM (MFMA bf16), 512 threads / 8 waves; wave w8 owns output slice w8 ----
    const int bid  = blockIdx.x - NB_BUCKET;
    const int w8   = tid >> 6;          // 0..7 -> output cols [w8*16, w8*16+16) = slice w8
    const int lane = tid & 63;
    const int quad = lane >> 4;
    const int m16  = lane & 15;
    const int row0 = bid * 64;

    // coalesced fragment loads: 8 x 16B per thread (same W1p slots as before)
    short8 bfr[8];
#pragma unroll
    for (int ks = 0; ks < 8; ++ks)
        bfr[ks] = ((const short8*)W1p)[(w8 * 8 + ks) * 64 + lane];

    // stage A tile -> bf16 LDS, swizzled; x is read-once -> non-temporal
#pragma unroll
    for (int it = 0; it < 4; ++it) {
        int id  = it * 512 + tid;
        int row = id >> 5;
        int kb  = id & 31;
        int gr  = row0 + row;
        float4v f0, f1;
        if (gr < NN) {
            const float4v* xp = (const float4v*)&x[(long long)gr * DIN + kb * 8];
            f0 = __builtin_nontemporal_load(xp);
            f1 = __builtin_nontemporal_load(xp + 1);
        } else {
            f0 = (float4v)(0.0f);
            f1 = (float4v)(0.0f);
        }
        short8 v;
        v[0] = (short)f2bf(f0[0]); v[1] = (short)f2bf(f0[1]);
        v[2] = (short)f2bf(f0[2]); v[3] = (short)f2bf(f0[3]);
        v[4] = (short)f2bf(f1[0]); v[5] = (short)f2bf(f1[1]);
        v[6] = (short)f2bf(f1[2]); v[7] = (short)f2bf(f1[3]);
        int chunk = row * 32 + (kb ^ (row & 31));
        *(short8*)&aL[chunk * 8] = v;
    }
    __syncthreads();

    float4v acc[4];
#pragma unroll
    for (int mt = 0; mt < 4; ++mt) acc[mt] = (float4v)(0.0f);

#pragma unroll
    for (int mt = 0; mt < 4; ++mt) {
        int row = mt * 16 + m16;
#pragma unroll
        for (int ks = 0; ks < 8; ++ks) {
            int kb = ks * 4 + quad;
            int chunk = row * 32 + (kb ^ (row & 31));
            short8 a = *(const short8*)&aL[chunk * 8];
            acc[mt] = __builtin_amdgcn_mfma_f32_16x16x32_bf16(a, bfr[ks], acc[mt], 0, 0, 0);
        }
    }

    // sliced epilogue: hs_s[w8][row][m16]
#pragma unroll
    for (int mt = 0; mt < 4; ++mt) {
#pragma unroll
        for (int r = 0; r < 4; ++r) {
            int row = row0 + mt * 16 + quad * 4 + r;
            if (row < NN)
                hs[((long long)w8 * NN + row) * 16 + m16] = f2bf(acc[mt][r]);
        }
    }
}

// ---------------- layer-1 aggregation + layer-2 linear, XCD-sliced over features ----------------
// Block (g, slice = blockIdx.x & 7): slice s stays on XCD s (bid%8 round-robin), whose L2
// holds the whole 3.2 MB hs slice -> per-XCD compulsory fetch only. Each wave: 8 nodes,
// 16 edges/round (4 lanes x uint2 = 4 bf16 features per edge). Edge 0 = self-loop (s=w).
// Per-slice partial dot with W2 is atomicAdd'ed into zs (zeroed by host memset).
__global__ __launch_bounds__(256) void k_agg1l2(const int* __restrict__ eidx,
                                                const int* __restrict__ excl,   // absolute
                                                const int* __restrict__ cnt,
                                                const unsigned* __restrict__ hs_s,
                                                const float* __restrict__ dinv,
                                                const float* __restrict__ b1,
                                                const float* __restrict__ W2,
                                                float* __restrict__ zs) {
    const int bid   = blockIdx.x;
    const int slice = bid & 7;
    const int g     = bid >> 3;
    const int tid   = threadIdx.x;
    const int lane  = tid & 63;
    const int wv    = tid >> 6;            // 0..3
    const int f4    = lane & 3;            // feature quad: features [slice*16+f4*4, +4)
    const int e16   = lane >> 2;           // edge group 0..15
    const uint2* hrow = (const uint2*)hs_s + (long long)slice * NN * 4;

    const float4 bb = ((const float4*)b1)[slice * 4 + f4];
    const float4 ww = ((const float4*)W2)[slice * 4 + f4];

    const int wbase = (g * 4 + wv) * 8;
    for (int ni = 0; ni < 8; ++ni) {
        int w = wbase + ni;
        if (w >= NN) break;                 // wave-uniform
        int offs = excl[w];
        int c    = cnt[w];
        float dw = dinv[w];
        float a0 = 0.f, a1 = 0.f, a2 = 0.f, a3 = 0.f;
        for (int j = 0; j <= c; j += 16) {  // virtual edges 0..c, 0 = self-loop
            int  eq    = j + e16;
            bool valid = (eq <= c);
            int  ld    = offs + ((valid && eq > 0) ? (eq - 1) : 0);
            int  sR    = __builtin_nontemporal_load(&eidx[ld]);   // stream, keep slice hot
            int  s     = (valid && eq > 0) ? sR : w;
            float e    = valid ? dinv[s] : 0.0f;                  // self weight = dinv[w]
            uint2 u    = hrow[(long long)s * 4 + f4];
            a0 = fmaf(e, bf_lo(u.x), a0);
            a1 = fmaf(e, bf_hi(u.x), a1);
            a2 = fmaf(e, bf_lo(u.y), a2);
            a3 = fmaf(e, bf_hi(u.y), a3);
        }
        // reduce over the 16 edge groups (xor masks 4..32 preserve f4)
#pragma unroll
        for (int m = 4; m <= 32; m <<= 1) {
            a0 += __shfl_xor(a0, m);
            a1 += __shfl_xor(a1, m);
            a2 += __shfl_xor(a2, m);
            a3 += __shfl_xor(a3, m);
        }
        float r0 = fmaxf(fmaf(dw, a0, bb.x), 0.0f);
        float r1 = fmaxf(fmaf(dw, a1, bb.y), 0.0f);
        float r2 = fmaxf(fmaf(dw, a2, bb.z), 0.0f);
        float r3 = fmaxf(fmaf(dw, a3, bb.w), 0.0f);
        float v = r0 * ww.x + r1 * ww.y + r2 * ww.z + r3 * ww.w;
        v += __shfl_xor(v, 1);
        v += __shfl_xor(v, 2);
        if (lane == 0) atomicAdd(&zs[w], dw * v);
    }
}

// ---------------- layer-2 aggregation + sigmoid epilogue (ILP-4) ----------------
__global__ void k_agg2_final(const int* __restrict__ eidx,
                             const int* __restrict__ excl,   // absolute
                             const int* __restrict__ cnt,
                             const float* __restrict__ zs,
                             const float* __restrict__ dinv,
                             const float* __restrict__ b2,
                             float* __restrict__ out) {
    int i = blockIdx.x * 256 + threadIdx.x;
    if (i >= NN) return;
    int offs = excl[i];
    int c = cnt[i];
    float v = zs[i];   // self-loop
    int j = 0;
    for (; j + 3 < c; j += 4) {
        int s0 = __builtin_nontemporal_load(&eidx[offs + j + 0]);
        int s1 = __builtin_nontemporal_load(&eidx[offs + j + 1]);
        int s2 = __builtin_nontemporal_load(&eidx[offs + j + 2]);
        int s3 = __builtin_nontemporal_load(&eidx[offs + j + 3]);
        v += zs[s0] + zs[s1] + zs[s2] + zs[s3];
    }
    for (; j < c; ++j) v += zs[eidx[offs + j]];
    float z = fmaf(dinv[i], v, b2[0]);
    out[i] = 1.0f / (1.0f + __expf(-z));
}

extern "C" void kernel_launch(void* const* d_in, const int* in_sizes, int n_in,
                              void* d_out, int out_size, void* d_ws, size_t ws_size,
                              hipStream_t stream) {
    const float* x  = (const float*)d_in[0];
    const int*   ei = (const int*)d_in[1];
    const float* W1 = (const float*)d_in[2];
    const float* b1 = (const float*)d_in[3];
    const float* W2 = (const float*)d_in[4];
    const float* b2 = (const float*)d_in[5];
    float* out = (float*)d_out;

    const int E = in_sizes[1] / 2;
    const int* src = ei;
    const int* dst = ei + E;

    // workspace layout (4-byte units; bucketArr 8B-aligned, hs 16B-aligned)
    int* wsi = (int*)d_ws;
    float* dinv       = (float*)wsi;                 // N
    int*   cnt        = wsi + NN;                    // N
    int*   excl       = cnt + NN;                    // N
    float* zs         = (float*)(excl + NN);         // N  (zeroed each launch; atomic target)
    int*   bucketFill = (int*)(zs + NN);             // 256
    unsigned short* W1p = (unsigned short*)(bucketFill + 256);  // 32768 bf16 (= 16384 ints)
    int*   eidx       = (int*)(W1p + 32768);         // E
    int2*  bucketArr  = (int2*)(eidx + E);           // NB_BUCKET*BCAP pairs (~19.3 MB)
    unsigned short* hs = (unsigned short*)(bucketArr + (long long)NB_BUCKET * BCAP);  // sliced [8][N][16] bf16

    const int nb_nodes = (NN + 255) / 256;
    const int pa_nb = (E + PA_EDGES - 1) / PA_EDGES;

    // zs and bucketFill are contiguous -> single memset clears both
    hipMemsetAsync(zs, 0, (NN + NB_BUCKET) * sizeof(int), stream);

    // launch 1: prepW (64 blocks) || partA (pa_nb blocks) — independent roots
    k_prep_partA<<<PREP_NB + pa_nb, 512, 0, stream>>>(W1, W1p, src, dst, E,
                                                      bucketFill, bucketArr);
    // launch 2: partB (196 blocks) || gemm (1563 blocks) — independent chains overlap
    k_gemm_partB<<<NB_BUCKET + GEMM_NB, 512, 0, stream>>>(x, W1p, hs, bucketFill, bucketArr,
                                                          cnt, excl, dinv, eidx);

    // launch 3: 8 slices x ceil(NN/32) node-groups; slice = bid&7 -> XCD affinity
    k_agg1l2<<<8 * ((NN + 31) / 32), 256, 0, stream>>>(eidx, excl, cnt,
                                                       (const unsigned*)hs, dinv, b1, W2, zs);

    k_agg2_final<<<nb_nodes, 256, 0, stream>>>(eidx, excl, cnt, zs, dinv, b2, out);
}